// Round 1
// baseline (209.254 us; speedup 1.0000x reference)
//
#include <hip/hip_runtime.h>
#include <stdint.h>

typedef unsigned short u16;

#define L_SEQ 2048
#define DMODEL 1024
#define NHEAD 16

using f32x4 = __attribute__((ext_vector_type(4))) float;
using s16x8 = __attribute__((ext_vector_type(8))) short;

__device__ __forceinline__ u16 f2b(float f) {
    union { float f; uint32_t u; } v; v.f = f;
    uint32_t r = v.u + 0x7fffu + ((v.u >> 16) & 1u);
    return (u16)(r >> 16);
}

__device__ __forceinline__ void gld16(const void* g, void* l) {
    __builtin_amdgcn_global_load_lds(
        (__attribute__((address_space(1))) void*)(uintptr_t)g,
        (__attribute__((address_space(3))) void*)(uintptr_t)l,
        16, 0, 0);
}

// ---------------- f32 -> bf16 convert ----------------
__global__ void k_tobf16(const float* __restrict__ src, u16* __restrict__ dst, int n8) {
    int i = blockIdx.x * blockDim.x + threadIdx.x;
    if (i >= n8) return;
    const float4* s4 = (const float4*)src;
    float4 a = s4[2 * i], b = s4[2 * i + 1];
    union { s16x8 v; u16 u[8]; } o;
    o.u[0] = f2b(a.x); o.u[1] = f2b(a.y); o.u[2] = f2b(a.z); o.u[3] = f2b(a.w);
    o.u[4] = f2b(b.x); o.u[5] = f2b(b.y); o.u[6] = f2b(b.z); o.u[7] = f2b(b.w);
    ((s16x8*)dst)[i] = o.v;
}

// ---------------- phase features: p = x @ Wp^T + bp, L2-normalize pairs ----------------
__global__ __launch_bounds__(256)
void k_phase(const float* __restrict__ x, const float* __restrict__ Wp,
             const float* __restrict__ bp,
             float* __restrict__ Cph, float* __restrict__ Sph) {
    const int tid = threadIdx.x;
    const int w = tid >> 6, lane = tid & 63;
    const int m = blockIdx.x * 4 + w;
    __shared__ float pbuf[4][32];
    float xr[16];
#pragma unroll
    for (int i = 0; i < 16; ++i) xr[i] = x[(size_t)m * DMODEL + lane + 64 * i];
#pragma unroll 4
    for (int n = 0; n < 32; ++n) {
        const float* wrow = Wp + n * DMODEL;
        float s = 0.f;
#pragma unroll
        for (int i = 0; i < 16; ++i) s += xr[i] * wrow[lane + 64 * i];
#pragma unroll
        for (int msk = 32; msk >= 1; msk >>= 1) s += __shfl_xor(s, msk);
        if (lane == 0) pbuf[w][n] = s + bp[n];
    }
    __syncthreads();
    if (lane < 16) {
        float c = pbuf[w][2 * lane], sn = pbuf[w][2 * lane + 1];
        float nrm = sqrtf(c * c + sn * sn);
        float inv = 1.0f / fmaxf(nrm, 1e-6f);
        Cph[lane * L_SEQ + m] = c * inv;
        Sph[lane * L_SEQ + m] = sn * inv;
    }
}

// ---------------- bf16 B^T GEMM: C[m,n] = sum_k A[m,k] * B[n,k] + bias[n] ----------------
// 128x128 tile, BK=64, 4 waves (2x2), global_load_lds staging (m97 structure).
template <int OUTF32>
__global__ __launch_bounds__(256, 2)
void k_gemm_bt(const u16* __restrict__ A,
               const u16* __restrict__ B0, const u16* __restrict__ B1, const u16* __restrict__ B2,
               const float* __restrict__ c0, const float* __restrict__ c1, const float* __restrict__ c2,
               void* __restrict__ Out, int ldo, int K) {
    __shared__ u16 As[128 * 64];
    __shared__ u16 Bs[128 * 64];
    const int tid = threadIdx.x;
    const int w = tid >> 6, lane = tid & 63;
    const int wr = w >> 1, wc = w & 1;
    const int u = lane & 15, g = lane >> 4;
    const int mt = blockIdx.x, nt = blockIdx.y;
    const int seg = nt >> 3, ntl = nt & 7;
    const u16* Bp = (seg == 0) ? B0 : (seg == 1) ? B1 : B2;
    const float* biasp = (seg == 0) ? c0 : (seg == 1) ? c1 : c2;

    const u16* Ab = A + (size_t)(mt * 128 + w * 32) * K;
    const u16* Bb = Bp + (size_t)(ntl * 128 + w * 32) * K;
    const int lr = lane >> 3;          // 0..7 row within 8-row chunk
    const int lc = (lane & 7) * 8;     // col offset (elements)

    f32x4 acc[4][4] = {};

    for (int k0 = 0; k0 < K; k0 += 64) {
#pragma unroll
        for (int c = 0; c < 4; ++c)
            gld16(Ab + (size_t)(c * 8 + lr) * K + k0 + lc, &As[(w * 32 + c * 8) * 64]);
#pragma unroll
        for (int c = 0; c < 4; ++c)
            gld16(Bb + (size_t)(c * 8 + lr) * K + k0 + lc, &Bs[(w * 32 + c * 8) * 64]);
        __syncthreads();
#pragma unroll
        for (int ks = 0; ks < 2; ++ks) {
            s16x8 af[4], bf[4];
#pragma unroll
            for (int i = 0; i < 4; ++i)
                af[i] = *(const s16x8*)&As[(wr * 64 + i * 16 + u) * 64 + ks * 32 + g * 8];
#pragma unroll
            for (int j = 0; j < 4; ++j)
                bf[j] = *(const s16x8*)&Bs[(wc * 64 + j * 16 + u) * 64 + ks * 32 + g * 8];
#pragma unroll
            for (int i = 0; i < 4; ++i)
#pragma unroll
                for (int j = 0; j < 4; ++j)
                    acc[i][j] = __builtin_amdgcn_mfma_f32_16x16x32_bf16(af[i], bf[j], acc[i][j], 0, 0, 0);
        }
        __syncthreads();
    }

#pragma unroll
    for (int i = 0; i < 4; ++i) {
#pragma unroll
        for (int j = 0; j < 4; ++j) {
            const int row0 = mt * 128 + wr * 64 + i * 16 + g * 4;
            const int col = nt * 128 + wc * 64 + j * 16 + u;
            const int colseg = ntl * 128 + wc * 64 + j * 16 + u;
            const float bias = biasp[colseg];
#pragma unroll
            for (int r = 0; r < 4; ++r) {
                float val = acc[i][j][r] + bias;
                if (OUTF32)
                    ((float*)Out)[(size_t)(row0 + r) * ldo + col] = val;
                else
                    ((u16*)Out)[(size_t)(row0 + r) * ldo + col] = f2b(val);
            }
        }
    }
}

// ---------------- fused attention with rank-2 phase bias ----------------
// grid: (L/64, H). 4 waves, each owns 16 q-rows. K tiles of 64 keys.
__global__ __launch_bounds__(256, 2)
void k_attn(const u16* __restrict__ QKV,
            const float* __restrict__ Cph, const float* __restrict__ Sph,
            const float* __restrict__ gamma,
            u16* __restrict__ Oout) {
    const int h = blockIdx.y;
    const int qb = blockIdx.x * 64;
    const int tid = threadIdx.x;
    const int w = tid >> 6, lane = tid & 63;
    const int u = lane & 15, g = lane >> 4;
    const int ld = 3 * DMODEL;

    __shared__ u16 Ks[64 * 64];
    __shared__ u16 Vt[64 * 64];
    __shared__ u16 Pl[4][16 * 64];

    const float gate = 0.08f / (1.0f + __expf(-gamma[h]));
    const u16* Qp = QKV + h * 64;
    const u16* Kp = QKV + DMODEL + h * 64;
    const u16* Vp = QKV + 2 * DMODEL + h * 64;

    s16x8 aq[2];
    {
        const int qrow = qb + w * 16 + u;
#pragma unroll
        for (int ks = 0; ks < 2; ++ks)
            aq[ks] = *(const s16x8*)(Qp + (size_t)qrow * ld + ks * 32 + g * 8);
    }
    float cq[4], sq[4];
#pragma unroll
    for (int r = 0; r < 4; ++r) {
        int qr = qb + w * 16 + g * 4 + r;
        cq[r] = Cph[h * L_SEQ + qr];
        sq[r] = Sph[h * L_SEQ + qr];
    }

    float mrow[4], lrow[4];
    f32x4 oacc[4] = {};
#pragma unroll
    for (int r = 0; r < 4; ++r) { mrow[r] = -1e30f; lrow[r] = 0.f; }

    char* KsB = (char*)Ks;
    char* VtB = (char*)Vt;
    char* PlB = (char*)&Pl[w][0];

    for (int kt = 0; kt < L_SEQ / 64; ++kt) {
        const int k0 = kt * 64;
        // stage K (row-swizzled) + V transposed
#pragma unroll
        for (int c = 0; c < 2; ++c) {
            const int r = c * 32 + tid / 8;
            const int d0 = (tid & 7) * 8;
            s16x8 kv = *(const s16x8*)(Kp + (size_t)(k0 + r) * ld + d0);
            int ba = r * 128 + d0 * 2; ba ^= (r & 7) << 4;
            *(s16x8*)(KsB + ba) = kv;
            union { s16x8 v; u16 us[8]; } vv;
            vv.v = *(const s16x8*)(Vp + (size_t)(k0 + r) * ld + d0);
#pragma unroll
            for (int i = 0; i < 8; ++i) {
                const int d = d0 + i;
                int vb = d * 128 + r * 2; vb ^= (d & 7) << 4;
                *(u16*)(VtB + vb) = vv.us[i];
            }
        }
        __syncthreads();

        // S = Q K^T  (per wave: 16q x 64k)
        f32x4 sf[4] = {};
#pragma unroll
        for (int kb = 0; kb < 4; ++kb) {
            const int j = kb * 16 + u;
#pragma unroll
            for (int ks = 0; ks < 2; ++ks) {
                int ba = j * 128 + (ks * 32 + g * 8) * 2; ba ^= (j & 7) << 4;
                s16x8 bk = *(const s16x8*)(KsB + ba);
                sf[kb] = __builtin_amdgcn_mfma_f32_16x16x32_bf16(aq[ks], bk, sf[kb], 0, 0, 0);
            }
        }

        // scale + rank-2 phase bias
        float ck[4], sk[4];
#pragma unroll
        for (int kb = 0; kb < 4; ++kb) {
            int kj = k0 + kb * 16 + u;
            ck[kb] = Cph[h * L_SEQ + kj];
            sk[kb] = Sph[h * L_SEQ + kj];
        }
        float sv[4][4], tmax[4];
#pragma unroll
        for (int r = 0; r < 4; ++r) tmax[r] = -1e30f;
#pragma unroll
        for (int kb = 0; kb < 4; ++kb)
#pragma unroll
            for (int r = 0; r < 4; ++r) {
                float xv = sf[kb][r] * 0.125f + gate * (cq[r] * ck[kb] + sq[r] * sk[kb]);
                sv[kb][r] = xv;
                tmax[r] = fmaxf(tmax[r], xv);
            }
#pragma unroll
        for (int r = 0; r < 4; ++r) {
#pragma unroll
            for (int msk = 1; msk <= 8; msk <<= 1)
                tmax[r] = fmaxf(tmax[r], __shfl_xor(tmax[r], msk));
        }
        float scale[4], tsum[4];
#pragma unroll
        for (int r = 0; r < 4; ++r) {
            float mn = fmaxf(mrow[r], tmax[r]);
            scale[r] = __expf(mrow[r] - mn);
            mrow[r] = mn;
            tsum[r] = 0.f;
        }
#pragma unroll
        for (int kb = 0; kb < 4; ++kb)
#pragma unroll
            for (int r = 0; r < 4; ++r) {
                float p = __expf(sv[kb][r] - mrow[r]);
                tsum[r] += p;
                int prow = g * 4 + r;
                int pb = prow * 128 + (kb * 16 + u) * 2; pb ^= (prow & 7) << 4;
                *(u16*)(PlB + pb) = f2b(p);
            }
#pragma unroll
        for (int r = 0; r < 4; ++r) {
#pragma unroll
            for (int msk = 1; msk <= 8; msk <<= 1)
                tsum[r] += __shfl_xor(tsum[r], msk);
            lrow[r] = lrow[r] * scale[r] + tsum[r];
        }
#pragma unroll
        for (int d = 0; d < 4; ++d)
#pragma unroll
            for (int r = 0; r < 4; ++r)
                oacc[d][r] *= scale[r];

        // O += P V
#pragma unroll
        for (int ks = 0; ks < 2; ++ks) {
            int pb = u * 128 + (ks * 32 + g * 8) * 2; pb ^= (u & 7) << 4;
            s16x8 pa = *(const s16x8*)(PlB + pb);
#pragma unroll
            for (int db = 0; db < 4; ++db) {
                int d = db * 16 + u;
                int vb = d * 128 + (ks * 32 + g * 8) * 2; vb ^= (d & 7) << 4;
                s16x8 bv = *(const s16x8*)(VtB + vb);
                oacc[db] = __builtin_amdgcn_mfma_f32_16x16x32_bf16(pa, bv, oacc[db], 0, 0, 0);
            }
        }
        __syncthreads();
    }

#pragma unroll
    for (int db = 0; db < 4; ++db)
#pragma unroll
        for (int r = 0; r < 4; ++r) {
            int qr = qb + w * 16 + g * 4 + r;
            int col = h * 64 + db * 16 + u;
            float val = oacc[db][r] / lrow[r];
            Oout[(size_t)qr * DMODEL + col] = f2b(val);
        }
}

extern "C" void kernel_launch(void* const* d_in, const int* in_sizes, int n_in,
                              void* d_out, int out_size, void* d_ws, size_t ws_size,
                              hipStream_t stream) {
    const float* x  = (const float*)d_in[0];
    const float* Wq = (const float*)d_in[1];
    const float* bq = (const float*)d_in[2];
    const float* Wk = (const float*)d_in[3];
    const float* bk = (const float*)d_in[4];
    const float* Wv = (const float*)d_in[5];
    const float* bv = (const float*)d_in[6];
    const float* Wo = (const float*)d_in[7];
    const float* bo = (const float*)d_in[8];
    const float* Wp = (const float*)d_in[9];
    const float* bp = (const float*)d_in[10];
    const float* gamma = (const float*)d_in[11];
    float* out = (float*)d_out;

    char* ws = (char*)d_ws;
    u16* xb = (u16*)ws;   ws += (size_t)L_SEQ * DMODEL * 2;
    u16* wqb = (u16*)ws;  ws += (size_t)DMODEL * DMODEL * 2;
    u16* wkb = (u16*)ws;  ws += (size_t)DMODEL * DMODEL * 2;
    u16* wvb = (u16*)ws;  ws += (size_t)DMODEL * DMODEL * 2;
    u16* wob = (u16*)ws;  ws += (size_t)DMODEL * DMODEL * 2;
    u16* qkv = (u16*)ws;  ws += (size_t)L_SEQ * 3 * DMODEL * 2;
    u16* attnb = (u16*)ws; ws += (size_t)L_SEQ * DMODEL * 2;
    float* Cph = (float*)ws; ws += (size_t)NHEAD * L_SEQ * 4;
    float* Sph = (float*)ws; ws += (size_t)NHEAD * L_SEQ * 4;

    const int nx8 = L_SEQ * DMODEL / 8;     // 262144
    const int nw8 = DMODEL * DMODEL / 8;    // 131072
    k_tobf16<<<(nx8 + 255) / 256, 256, 0, stream>>>(x, xb, nx8);
    k_tobf16<<<(nw8 + 255) / 256, 256, 0, stream>>>(Wq, wqb, nw8);
    k_tobf16<<<(nw8 + 255) / 256, 256, 0, stream>>>(Wk, wkb, nw8);
    k_tobf16<<<(nw8 + 255) / 256, 256, 0, stream>>>(Wv, wvb, nw8);
    k_tobf16<<<(nw8 + 255) / 256, 256, 0, stream>>>(Wo, wob, nw8);

    k_phase<<<L_SEQ / 4, 256, 0, stream>>>(x, Wp, bp, Cph, Sph);

    // fused QKV projection -> qkv [2048, 3072] bf16
    k_gemm_bt<0><<<dim3(16, 24), 256, 0, stream>>>(xb, wqb, wkb, wvb, bq, bk, bv,
                                                   (void*)qkv, 3 * DMODEL, DMODEL);

    k_attn<<<dim3(L_SEQ / 64, NHEAD), 256, 0, stream>>>(qkv, Cph, Sph, gamma, attnb);

    // output projection -> d_out f32 [2048, 1024]
    k_gemm_bt<1><<<dim3(16, 8), 256, 0, stream>>>(attnb, wob, wob, wob, bo, bo, bo,
                                                  (void*)out, DMODEL, DMODEL);
}

// Round 4
// 152.376 us; speedup vs baseline: 1.3733x; 1.3733x over previous
//
#include <hip/hip_runtime.h>
#include <stdint.h>

typedef unsigned short u16;

#define L_SEQ 2048
#define DMODEL 1024
#define NHEAD 16

using f32x4 = __attribute__((ext_vector_type(4))) float;
using s16x8 = __attribute__((ext_vector_type(8))) short;

__device__ __forceinline__ u16 f2b(float f) {
    union { float f; uint32_t u; } v; v.f = f;
    uint32_t r = v.u + 0x7fffu + ((v.u >> 16) & 1u);
    return (u16)(r >> 16);
}

__device__ __forceinline__ void gld16(const void* g, void* l) {
    __builtin_amdgcn_global_load_lds(
        (__attribute__((address_space(1))) void*)(uintptr_t)g,
        (__attribute__((address_space(3))) void*)(uintptr_t)l,
        16, 0, 0);
}

// ---------------- fused f32 -> bf16 convert (x + 4 weights, one launch) ----------------
__global__ __launch_bounds__(256)
void k_tobf16_all(const float* __restrict__ x, const float* __restrict__ wq,
                  const float* __restrict__ wk, const float* __restrict__ wv,
                  const float* __restrict__ wo,
                  u16* __restrict__ xb, u16* __restrict__ wqb, u16* __restrict__ wkb,
                  u16* __restrict__ wvb, u16* __restrict__ wob) {
    const int NX = L_SEQ * DMODEL / 8;     // 262144
    const int NW = DMODEL * DMODEL / 8;    // 131072 = 2^17
    int i = blockIdx.x * blockDim.x + threadIdx.x;
    const float* src; u16* dst; int j;
    if (i < NX) { src = x; dst = xb; j = i; }
    else {
        int t = i - NX; int sel = t >> 17; j = t & (NW - 1);
        src = (sel == 0) ? wq : (sel == 1) ? wk : (sel == 2) ? wv : wo;
        dst = (sel == 0) ? wqb : (sel == 1) ? wkb : (sel == 2) ? wvb : wob;
    }
    const float4* s4 = (const float4*)src;
    float4 a = s4[2 * j], b = s4[2 * j + 1];
    union { s16x8 v; u16 u[8]; } o;
    o.u[0] = f2b(a.x); o.u[1] = f2b(a.y); o.u[2] = f2b(a.z); o.u[3] = f2b(a.w);
    o.u[4] = f2b(b.x); o.u[5] = f2b(b.y); o.u[6] = f2b(b.z); o.u[7] = f2b(b.w);
    ((s16x8*)dst)[j] = o.v;
}

// ---------------- phase features (verified R1) ----------------
__global__ __launch_bounds__(256)
void k_phase(const float* __restrict__ x, const float* __restrict__ Wp,
             const float* __restrict__ bp,
             float* __restrict__ Cph, float* __restrict__ Sph) {
    const int tid = threadIdx.x;
    const int w = tid >> 6, lane = tid & 63;
    const int m = blockIdx.x * 4 + w;
    __shared__ float pbuf[4][32];
    float xr[16];
#pragma unroll
    for (int i = 0; i < 16; ++i) xr[i] = x[(size_t)m * DMODEL + lane + 64 * i];
#pragma unroll 4
    for (int n = 0; n < 32; ++n) {
        const float* wrow = Wp + n * DMODEL;
        float s = 0.f;
#pragma unroll
        for (int i = 0; i < 16; ++i) s += xr[i] * wrow[lane + 64 * i];
#pragma unroll
        for (int msk = 32; msk >= 1; msk >>= 1) s += __shfl_xor(s, msk);
        if (lane == 0) pbuf[w][n] = s + bp[n];
    }
    __syncthreads();
    if (lane < 16) {
        float c = pbuf[w][2 * lane], sn = pbuf[w][2 * lane + 1];
        float nrm = sqrtf(c * c + sn * sn);
        float inv = 1.0f / fmaxf(nrm, 1e-6f);
        Cph[lane * L_SEQ + m] = c * inv;
        Sph[lane * L_SEQ + m] = sn * inv;
    }
}

// ---------------- bf16 B^T GEMM (m97 structure, verified R1 — unchanged) ----------------
template <int OUTF32>
__global__ __launch_bounds__(256, 2)
void k_gemm_bt(const u16* __restrict__ A,
               const u16* __restrict__ B0, const u16* __restrict__ B1, const u16* __restrict__ B2,
               const float* __restrict__ c0, const float* __restrict__ c1, const float* __restrict__ c2,
               void* __restrict__ Out, int ldo, int K) {
    __shared__ u16 As[128 * 64];
    __shared__ u16 Bs[128 * 64];
    const int tid = threadIdx.x;
    const int w = tid >> 6, lane = tid & 63;
    const int wr = w >> 1, wc = w & 1;
    const int u = lane & 15, g = lane >> 4;
    const int mt = blockIdx.x, nt = blockIdx.y;
    const int seg = nt >> 3, ntl = nt & 7;
    const u16* Bp = (seg == 0) ? B0 : (seg == 1) ? B1 : B2;
    const float* biasp = (seg == 0) ? c0 : (seg == 1) ? c1 : c2;

    const u16* Ab = A + (size_t)(mt * 128 + w * 32) * K;
    const u16* Bb = Bp + (size_t)(ntl * 128 + w * 32) * K;
    const int lr = lane >> 3;
    const int lc = (lane & 7) * 8;

    f32x4 acc[4][4] = {};

    for (int k0 = 0; k0 < K; k0 += 64) {
#pragma unroll
        for (int c = 0; c < 4; ++c)
            gld16(Ab + (size_t)(c * 8 + lr) * K + k0 + lc, &As[(w * 32 + c * 8) * 64]);
#pragma unroll
        for (int c = 0; c < 4; ++c)
            gld16(Bb + (size_t)(c * 8 + lr) * K + k0 + lc, &Bs[(w * 32 + c * 8) * 64]);
        __syncthreads();
#pragma unroll
        for (int ks = 0; ks < 2; ++ks) {
            s16x8 af[4], bf[4];
#pragma unroll
            for (int i = 0; i < 4; ++i)
                af[i] = *(const s16x8*)&As[(wr * 64 + i * 16 + u) * 64 + ks * 32 + g * 8];
#pragma unroll
            for (int j = 0; j < 4; ++j)
                bf[j] = *(const s16x8*)&Bs[(wc * 64 + j * 16 + u) * 64 + ks * 32 + g * 8];
#pragma unroll
            for (int i = 0; i < 4; ++i)
#pragma unroll
                for (int j = 0; j < 4; ++j)
                    acc[i][j] = __builtin_amdgcn_mfma_f32_16x16x32_bf16(af[i], bf[j], acc[i][j], 0, 0, 0);
        }
        __syncthreads();
    }

#pragma unroll
    for (int i = 0; i < 4; ++i) {
#pragma unroll
        for (int j = 0; j < 4; ++j) {
            const int row0 = mt * 128 + wr * 64 + i * 16 + g * 4;
            const int col = nt * 128 + wc * 64 + j * 16 + u;
            const int colseg = ntl * 128 + wc * 64 + j * 16 + u;
            const float bias = biasp[colseg];
#pragma unroll
            for (int r = 0; r < 4; ++r) {
                float val = acc[i][j][r] + bias;
                if (OUTF32)
                    ((float*)Out)[(size_t)(row0 + r) * ldo + col] = val;
                else
                    ((u16*)Out)[(size_t)(row0 + r) * ldo + col] = f2b(val);
            }
        }
    }
}

// ---------------- V transpose: qkv V section [token][feat] -> VtG [feat][token] ----------------
__global__ __launch_bounds__(256)
void k_transposeV(const u16* __restrict__ qkv, u16* __restrict__ VtG) {
    __shared__ u16 T[64 * 64];   // byte(r,c) = r*128 + ((c*2) ^ ((((r>>3)^r)&7)<<4))
    const int tb = blockIdx.x;   // token block (64 tokens)
    const int fb = blockIdx.y;   // feature block (64 feats)
    const int tid = threadIdx.x;
    char* Tb = (char*)T;
#pragma unroll
    for (int t = 0; t < 2; ++t) {
        int ci = t * 256 + tid;
        int r = ci >> 3, cb = ci & 7;
        s16x8 v = *(const s16x8*)(qkv + (size_t)(tb * 64 + r) * (3 * DMODEL) + 2 * DMODEL + fb * 64 + cb * 8);
        int kk = (((r >> 3) ^ r) & 7) << 4;
        *(s16x8*)(Tb + r * 128 + ((cb * 16) ^ kk)) = v;
    }
    __syncthreads();
#pragma unroll
    for (int t = 0; t < 2; ++t) {
        int co = t * 256 + tid;
        int f = co >> 3, t8 = co & 7;
        union { u16 us[8]; s16x8 v; } o;
#pragma unroll
        for (int x = 0; x < 8; ++x) {
            int r = t8 * 8 + x;
            int kk = (((r >> 3) ^ r) & 7) << 4;
            o.us[x] = *(const u16*)(Tb + r * 128 + ((f * 2) ^ kk));
        }
        *(s16x8*)(VtG + (size_t)(fb * 64 + f) * L_SEQ + tb * 64 + t8 * 8) = o.v;
    }
}

// ---------------- fused attention v3 ----------------
// grid (L/64, H), 4 waves x 16 q-rows. K and V^T both staged via gld16 with
// pre-swizzled sources (verified K pattern), double-buffered, 1 barrier/tile.
// P path identical to verified R1 (Pl scalar writes, vector reads).
__global__ __launch_bounds__(256, 2)
void k_attn(const u16* __restrict__ QKV, const u16* __restrict__ VtG,
            const float* __restrict__ Cph, const float* __restrict__ Sph,
            const float* __restrict__ gamma, u16* __restrict__ Oout) {
    const int h = blockIdx.y;
    const int qb = blockIdx.x * 64;
    const int tid = threadIdx.x;
    const int w = tid >> 6, lane = tid & 63;
    const int u = lane & 15, g = lane >> 4;
    const int ld = 3 * DMODEL;
    const int NT = L_SEQ / 64;
    const int BUF = 64 * 64 * 2;

    // Ks: byte(row,d) = row*128 + ((d*2) ^ ((row&7)<<4))   row = key idx
    // Vs: byte(row,k) = row*128 + ((k*2) ^ ((row&7)<<4))   row = d idx (V^T)
    __shared__ u16 Ks[2][64 * 64];
    __shared__ u16 Vs[2][64 * 64];
    __shared__ u16 Pl[4][16 * 64];  // byte(q,kk) = q*128 + ((kk*2) ^ ((q&7)<<4)) per wave

    const float gate = 0.08f / (1.0f + __expf(-gamma[h]));
    const u16* Qp = QKV + h * 64;
    const u16* Kp = QKV + DMODEL + h * 64;
    const u16* VtH = VtG + (size_t)h * 64 * L_SEQ;
    const float* CphH = Cph + h * L_SEQ;
    const float* SphH = Sph + h * L_SEQ;

    s16x8 aq[2];
    {
        const int qrow = qb + w * 16 + u;
        aq[0] = *(const s16x8*)(Qp + (size_t)qrow * ld + g * 8);
        aq[1] = *(const s16x8*)(Qp + (size_t)qrow * ld + 32 + g * 8);
    }
    float gcq[4], gsq[4];
#pragma unroll
    for (int r = 0; r < 4; ++r) {
        int qr = qb + w * 16 + g * 4 + r;
        gcq[r] = gate * CphH[qr];
        gsq[r] = gate * SphH[qr];
    }

    // staging addresses: pre-swizzled global source, linear LDS dest
    unsigned dstOff[2];
    size_t srcK[2], srcV[2];
#pragma unroll
    for (int t = 0; t < 2; ++t) {
        int ci = (w * 2 + t) * 64 + lane;
        int row = ci >> 3, cb = ci & 7;
        dstOff[t] = (unsigned)((w * 2 + t) * 1024);
        srcK[t] = (size_t)row * ld + (size_t)((cb ^ (row & 7)) * 8);
        srcV[t] = (size_t)row * L_SEQ + (size_t)((cb ^ (row & 7)) * 8);
    }
    char* ksBase = (char*)Ks;
    char* vsBase = (char*)Vs;
    char* PlB = (char*)Pl + w * 2048;

    // prologue: stage tile 0 into buffer 0
#pragma unroll
    for (int t = 0; t < 2; ++t) {
        gld16(Kp + srcK[t], ksBase + dstOff[t]);
        gld16(VtH + srcV[t], vsBase + dstOff[t]);
    }
    __syncthreads();

    float mrow[4], lrow[4];
    f32x4 oacc[4] = {};
#pragma unroll
    for (int r = 0; r < 4; ++r) { mrow[r] = -1e30f; lrow[r] = 0.f; }

    for (int kt = 0; kt < NT; ++kt) {
        const int cur = kt & 1;
        char* kCur = ksBase + cur * BUF;
        char* vCur = vsBase + cur * BUF;
        if (kt + 1 < NT) {
            const u16* Kn = Kp + (size_t)(kt + 1) * 64 * ld;
            const u16* Vn = VtH + (size_t)(kt + 1) * 64;
            char* kN = ksBase + (cur ^ 1) * BUF;
            char* vN = vsBase + (cur ^ 1) * BUF;
#pragma unroll
            for (int t = 0; t < 2; ++t) {
                gld16(Kn + srcK[t], kN + dstOff[t]);
                gld16(Vn + srcV[t], vN + dstOff[t]);
            }
        }

        // ---- S = Q K^T ----
        f32x4 sf[4] = {};
        const int x0 = (g * 16) ^ ((u & 7) << 4);
#pragma unroll
        for (int kb = 0; kb < 4; ++kb) {
            const int rowb = (kb * 16 + u) * 128;
            s16x8 b0 = *(const s16x8*)(kCur + rowb + x0);
            s16x8 b1 = *(const s16x8*)(kCur + rowb + (x0 ^ 64));
            sf[kb] = __builtin_amdgcn_mfma_f32_16x16x32_bf16(aq[0], b0, sf[kb], 0, 0, 0);
            sf[kb] = __builtin_amdgcn_mfma_f32_16x16x32_bf16(aq[1], b1, sf[kb], 0, 0, 0);
        }

        // ---- bias + online softmax (verified R1 math) ----
        float ck4[4], sk4[4];
#pragma unroll
        for (int kb = 0; kb < 4; ++kb) {
            int kj = kt * 64 + kb * 16 + u;
            ck4[kb] = CphH[kj];
            sk4[kb] = SphH[kj];
        }
        float sv[4][4], tmax[4];
#pragma unroll
        for (int r = 0; r < 4; ++r) tmax[r] = -1e30f;
#pragma unroll
        for (int kb = 0; kb < 4; ++kb)
#pragma unroll
            for (int r = 0; r < 4; ++r) {
                float xv = sf[kb][r] * 0.125f + gcq[r] * ck4[kb] + gsq[r] * sk4[kb];
                sv[kb][r] = xv;
                tmax[r] = fmaxf(tmax[r], xv);
            }
#pragma unroll
        for (int r = 0; r < 4; ++r) {
#pragma unroll
            for (int msk = 1; msk <= 8; msk <<= 1)
                tmax[r] = fmaxf(tmax[r], __shfl_xor(tmax[r], msk));
        }
        float scl[4], tsum[4];
#pragma unroll
        for (int r = 0; r < 4; ++r) {
            float mn = fmaxf(mrow[r], tmax[r]);
            scl[r] = __expf(mrow[r] - mn);
            mrow[r] = mn;
            tsum[r] = 0.f;
        }
#pragma unroll
        for (int kb = 0; kb < 4; ++kb)
#pragma unroll
            for (int r = 0; r < 4; ++r) {
                float p = __expf(sv[kb][r] - mrow[r]);
                tsum[r] += p;
                int prow = g * 4 + r;
                int pb = prow * 128 + (kb * 16 + u) * 2;
                pb ^= (prow & 7) << 4;
                *(u16*)(PlB + pb) = f2b(p);
            }
#pragma unroll
        for (int r = 0; r < 4; ++r) {
#pragma unroll
            for (int msk = 1; msk <= 8; msk <<= 1)
                tsum[r] += __shfl_xor(tsum[r], msk);
            lrow[r] = lrow[r] * scl[r] + tsum[r];
        }
#pragma unroll
        for (int db = 0; db < 4; ++db)
#pragma unroll
            for (int r = 0; r < 4; ++r)
                oacc[db][r] *= scl[r];

        // ---- O += P V : P from Pl (R1 pattern), V from V^T rows (contiguous) ----
#pragma unroll
        for (int ks = 0; ks < 2; ++ks) {
            const int xv = (ks * 64 + g * 16) ^ ((u & 7) << 4);
            s16x8 pa = *(const s16x8*)(PlB + u * 128 + xv);
#pragma unroll
            for (int db = 0; db < 4; ++db) {
                s16x8 bv = *(const s16x8*)(vCur + (db * 16 + u) * 128 + xv);
                oacc[db] = __builtin_amdgcn_mfma_f32_16x16x32_bf16(pa, bv, oacc[db], 0, 0, 0);
            }
        }
        __syncthreads();
    }

#pragma unroll
    for (int db = 0; db < 4; ++db)
#pragma unroll
        for (int r = 0; r < 4; ++r) {
            int qr = qb + w * 16 + g * 4 + r;
            int col = h * 64 + db * 16 + u;
            Oout[(size_t)qr * DMODEL + col] = f2b(oacc[db][r] / lrow[r]);
        }
}

extern "C" void kernel_launch(void* const* d_in, const int* in_sizes, int n_in,
                              void* d_out, int out_size, void* d_ws, size_t ws_size,
                              hipStream_t stream) {
    const float* x  = (const float*)d_in[0];
    const float* Wq = (const float*)d_in[1];
    const float* bq = (const float*)d_in[2];
    const float* Wk = (const float*)d_in[3];
    const float* bk = (const float*)d_in[4];
    const float* Wv = (const float*)d_in[5];
    const float* bv = (const float*)d_in[6];
    const float* Wo = (const float*)d_in[7];
    const float* bo = (const float*)d_in[8];
    const float* Wp = (const float*)d_in[9];
    const float* bp = (const float*)d_in[10];
    const float* gamma = (const float*)d_in[11];
    float* out = (float*)d_out;

    char* ws = (char*)d_ws;
    u16* xb = (u16*)ws;   ws += (size_t)L_SEQ * DMODEL * 2;
    u16* wqb = (u16*)ws;  ws += (size_t)DMODEL * DMODEL * 2;
    u16* wkb = (u16*)ws;  ws += (size_t)DMODEL * DMODEL * 2;
    u16* wvb = (u16*)ws;  ws += (size_t)DMODEL * DMODEL * 2;
    u16* wob = (u16*)ws;  ws += (size_t)DMODEL * DMODEL * 2;
    u16* qkv = (u16*)ws;  ws += (size_t)L_SEQ * 3 * DMODEL * 2;
    u16* attnb = (u16*)ws; ws += (size_t)L_SEQ * DMODEL * 2;
    u16* VtG = (u16*)ws;  ws += (size_t)DMODEL * L_SEQ * 2;
    float* Cph = (float*)ws; ws += (size_t)NHEAD * L_SEQ * 4;
    float* Sph = (float*)ws; ws += (size_t)NHEAD * L_SEQ * 4;

    const int ntot8 = (L_SEQ * DMODEL + 4 * DMODEL * DMODEL) / 8;  // 786432
    k_tobf16_all<<<ntot8 / 256, 256, 0, stream>>>(x, Wq, Wk, Wv, Wo, xb, wqb, wkb, wvb, wob);

    k_phase<<<L_SEQ / 4, 256, 0, stream>>>(x, Wp, bp, Cph, Sph);

    // fused QKV projection -> qkv [2048, 3072] bf16
    k_gemm_bt<0><<<dim3(16, 24), 256, 0, stream>>>(xb, wqb, wkb, wvb, bq, bk, bv,
                                                   (void*)qkv, 3 * DMODEL, DMODEL);

    // V^T [1024, 2048] bf16
    k_transposeV<<<dim3(L_SEQ / 64, DMODEL / 64), 256, 0, stream>>>(qkv, VtG);

    k_attn<<<dim3(L_SEQ / 64, NHEAD), 256, 0, stream>>>(qkv, VtG, Cph, Sph, gamma, attnb);

    // output projection -> d_out f32 [2048, 1024]
    k_gemm_bt<1><<<dim3(16, 8), 256, 0, stream>>>(attnb, wob, wob, wob, bo, bo, bo,
                                                  (void*)out, DMODEL, DMODEL);
}